// Round 7
// baseline (144.505 us; speedup 1.0000x reference)
//
#include <hip/hip_runtime.h>

// Problem constants (compile-time, from reference):
//   B=2, D=H=W=160, C=2, N_LABELS=25, MAX_LABEL=48
//   voxels/batch V = 160^3 = 4,096,000 ; total voxels = 8,192,000
#define VPB   4096000
#define NLAB  25
#define MAXL  48
#define TOTAL_VOX 8192000

// Inverse LUT: FreeSurfer label value -> row index in means/stds.
// GEN_LABELS = {0,2,3,4,5,7,8,10,11,12,13,14,15,16,17,18,24,26,28,41,42,43,44,46,47}
__device__ __constant__ int c_lut[MAXL] = {
    /* 0*/ 0, /* 1*/ 0, /* 2*/ 1, /* 3*/ 2, /* 4*/ 3, /* 5*/ 4, /* 6*/ 0, /* 7*/ 5,
    /* 8*/ 6, /* 9*/ 0, /*10*/ 7, /*11*/ 8, /*12*/ 9, /*13*/10, /*14*/11, /*15*/12,
    /*16*/13, /*17*/14, /*18*/15, /*19*/ 0, /*20*/ 0, /*21*/ 0, /*22*/ 0, /*23*/ 0,
    /*24*/16, /*25*/ 0, /*26*/17, /*27*/ 0, /*28*/18, /*29*/ 0, /*30*/ 0, /*31*/ 0,
    /*32*/ 0, /*33*/ 0, /*34*/ 0, /*35*/ 0, /*36*/ 0, /*37*/ 0, /*38*/ 0, /*39*/ 0,
    /*40*/ 0, /*41*/19, /*42*/20, /*43*/21, /*44*/22, /*45*/ 0, /*46*/23, /*47*/24
};

// One thread handles 4 consecutive voxels. Grid: 8000 x 256 (best measured
// granularity — r4/r5 showed larger per-thread tiles regress).
// Round-3 lesson: NO nontemporal stores (1.74x WRITE_SIZE amplification).
// Round-7 change: NO __syncthreads. Each wave builds its own private
// 96-entry LDS table (redundant 1.5 KB of L1-hot global gather loads per
// wave); same-wave ds_write->ds_read needs only lgkmcnt, so the block-wide
// barrier (which forced vmcnt(0) resync of all waves to the slowest table
// load) disappears entirely. Kernel is now a pure unsynchronized stream.
__global__ __launch_bounds__(256) void gmm_sample_kernel(
    const int*   __restrict__ labels,   // [B*V] (trailing dim 1 squeezed)
    const float* __restrict__ means,    // [B, 25, 2]
    const float* __restrict__ stds,     // [B, 25, 2]
    const float* __restrict__ noise,    // [B*V, 2]
    float*       __restrict__ out)      // [B*V, 2]
{
    // Per-wave private tables: 4 waves x 96 entries x 16 B = 6 KB/block.
    __shared__ float4 table[4 * 2 * MAXL];

    const int tid   = threadIdx.x;
    const int lane  = tid & 63;
    const int wslot = tid >> 6;

    const int g  = blockIdx.x * 256 + tid;      // thread id, < 2,048,000
    const int v0 = g << 2;                      // first voxel, < 8,192,000

    // ---- stream loads first: in flight during the table build ----
    const int4   lab = *(const int4*)  (labels + v0);
    const float4 n0  = *(const float4*)(noise + ((size_t)v0 << 1));
    const float4 n1  = *(const float4*)(noise + ((size_t)v0 << 1) + 4);

    // ---- per-wave fused table: (mean0, mean1, std0, std1) per label value ----
    float4* wtab = &table[wslot * (2 * MAXL)];
    #pragma unroll
    for (int e = lane; e < 2 * MAXL; e += 64) {
        const int b   = (e >= MAXL) ? 1 : 0;
        const int lv  = e - b * MAXL;
        const int row = c_lut[lv];
        const float2 m = *(const float2*)(means + ((b * NLAB + row) << 1));
        const float2 s = *(const float2*)(stds  + ((b * NLAB + row) << 1));
        wtab[e] = make_float4(m.x, m.y, s.x, s.y);
    }
    // No barrier: each wave reads only its own wtab (lgkmcnt handles the
    // ds_write -> ds_read dependency within the wave).

    // Batch boundary (4,096,000) is a multiple of 4 -> all 4 voxels same batch.
    const int boff = (v0 >= VPB) ? MAXL : 0;

    const float4 e0 = wtab[boff + lab.x];
    const float4 e1 = wtab[boff + lab.y];
    const float4 e2 = wtab[boff + lab.z];
    const float4 e3 = wtab[boff + lab.w];

    float4 o0, o1;
    o0.x = fmaf(e0.z, n0.x, e0.x);
    o0.y = fmaf(e0.w, n0.y, e0.y);
    o0.z = fmaf(e1.z, n0.z, e1.x);
    o0.w = fmaf(e1.w, n0.w, e1.y);
    o1.x = fmaf(e2.z, n1.x, e2.x);
    o1.y = fmaf(e2.w, n1.y, e2.y);
    o1.z = fmaf(e3.z, n1.z, e3.x);
    o1.w = fmaf(e3.w, n1.w, e3.y);

    *(float4*)(out + ((size_t)v0 << 1))     = o0;
    *(float4*)(out + ((size_t)v0 << 1) + 4) = o1;
}

extern "C" void kernel_launch(void* const* d_in, const int* in_sizes, int n_in,
                              void* d_out, int out_size, void* d_ws, size_t ws_size,
                              hipStream_t stream) {
    const int*   labels = (const int*)  d_in[0];  // [2,160,160,160,1] int32
    const float* means  = (const float*)d_in[1];  // [2,25,2] f32
    const float* stds   = (const float*)d_in[2];  // [2,25,2] f32
    const float* noise  = (const float*)d_in[3];  // [2,160,160,160,2] f32
    float* out = (float*)d_out;                   // [2,160,160,160,2] f32

    const int threads = 256;
    const int total_threads = TOTAL_VOX / 4;      // 2,048,000
    const int blocks = total_threads / threads;   // 8000
    gmm_sample_kernel<<<blocks, threads, 0, stream>>>(labels, means, stds, noise, out);
}

// Round 8
// 144.000 us; speedup vs baseline: 1.0035x; 1.0035x over previous
//
#include <hip/hip_runtime.h>

// Problem constants (compile-time, from reference):
//   B=2, D=H=W=160, C=2, N_LABELS=25, MAX_LABEL=48
//   voxels/batch V = 160^3 = 4,096,000 ; total voxels = 8,192,000
#define VPB   4096000
#define NLAB  25
#define MAXL  48
#define TOTAL_VOX 8192000

// Grid-stride config: 2000 blocks x 256 thr = 512,000 threads; 4 iterations
// of one 4-voxel chunk each; stride = 512,000 chunks = 2,048,000 voxels.
// Iterations 0,1 cover batch 0 exactly; 2,3 cover batch 1 (boundary at
// 2 * 2,048,000 = 4,096,000 = VPB) -> boff is compile-time per iteration.
#define NTHREADS_TOT 512000
#define ITER_VOX     2048000

// Inverse LUT: FreeSurfer label value -> row index in means/stds.
// GEN_LABELS = {0,2,3,4,5,7,8,10,11,12,13,14,15,16,17,18,24,26,28,41,42,43,44,46,47}
__device__ __constant__ int c_lut[MAXL] = {
    /* 0*/ 0, /* 1*/ 0, /* 2*/ 1, /* 3*/ 2, /* 4*/ 3, /* 5*/ 4, /* 6*/ 0, /* 7*/ 5,
    /* 8*/ 6, /* 9*/ 0, /*10*/ 7, /*11*/ 8, /*12*/ 9, /*13*/10, /*14*/11, /*15*/12,
    /*16*/13, /*17*/14, /*18*/15, /*19*/ 0, /*20*/ 0, /*21*/ 0, /*22*/ 0, /*23*/ 0,
    /*24*/16, /*25*/ 0, /*26*/17, /*27*/ 0, /*28*/18, /*29*/ 0, /*30*/ 0, /*31*/ 0,
    /*32*/ 0, /*33*/ 0, /*34*/ 0, /*35*/ 0, /*36*/ 0, /*37*/ 0, /*38*/ 0, /*39*/ 0,
    /*40*/ 0, /*41*/19, /*42*/20, /*43*/21, /*44*/22, /*45*/ 0, /*46*/23, /*47*/24
};

// Round-3 lesson: NO nontemporal stores (1.74x WRITE_SIZE amplification).
// Round-8: persistent grid-stride waves with cross-iteration prefetch —
// next iteration's label+noise loads are in flight while the current
// iteration gathers/FMAs/stores. Amortizes table build, block setup/drain,
// and the load->use latency chain over 4 iterations per wave.
__global__ __launch_bounds__(256) void gmm_sample_kernel(
    const int*   __restrict__ labels,   // [B*V] (trailing dim 1 squeezed)
    const float* __restrict__ means,    // [B, 25, 2]
    const float* __restrict__ stds,     // [B, 25, 2]
    const float* __restrict__ noise,    // [B*V, 2]
    float*       __restrict__ out)      // [B*V, 2]
{
    __shared__ float4 table[2 * MAXL];

    const int tid  = threadIdx.x;
    const int base = blockIdx.x * 256 + tid;    // chunk id, < 512,000
    const size_t v0base = (size_t)base << 2;    // first voxel of chunk

    // ---- iteration-0 stream loads first: in flight during table build ----
    int4   lab = *(const int4*)  (labels + v0base);
    float4 cn0 = *(const float4*)(noise + (v0base << 1));
    float4 cn1 = *(const float4*)(noise + (v0base << 1) + 4);

    // ---- fused per-(batch,label-value) table: (mean0, mean1, std0, std1) ----
    if (tid < 2 * MAXL) {
        const int b = tid / MAXL;
        const int v = tid - b * MAXL;
        const int row = c_lut[v];
        const float* mp = means + ((b * NLAB + row) << 1);
        const float* sp = stds  + ((b * NLAB + row) << 1);
        table[tid] = make_float4(mp[0], mp[1], sp[0], sp[1]);
    }
    __syncthreads();

    #pragma unroll
    for (int i = 0; i < 4; ++i) {
        const size_t v0 = v0base + (size_t)i * ITER_VOX;

        // Capture current iteration's operands.
        const int4   l  = lab;
        const float4 n0 = cn0;
        const float4 n1 = cn1;

        // Prefetch next iteration (addresses independent of current compute).
        if (i < 3) {
            const size_t vn = v0base + (size_t)(i + 1) * ITER_VOX;
            lab = *(const int4*)  (labels + vn);
            cn0 = *(const float4*)(noise + (vn << 1));
            cn1 = *(const float4*)(noise + (vn << 1) + 4);
        }

        // Compile-time batch offset: iterations 0,1 -> batch 0; 2,3 -> batch 1.
        const int boff = (i >= 2) ? MAXL : 0;

        const float4 e0 = table[boff + l.x];
        const float4 e1 = table[boff + l.y];
        const float4 e2 = table[boff + l.z];
        const float4 e3 = table[boff + l.w];

        float4 o0, o1;
        o0.x = fmaf(e0.z, n0.x, e0.x);
        o0.y = fmaf(e0.w, n0.y, e0.y);
        o0.z = fmaf(e1.z, n0.z, e1.x);
        o0.w = fmaf(e1.w, n0.w, e1.y);
        o1.x = fmaf(e2.z, n1.x, e2.x);
        o1.y = fmaf(e2.w, n1.y, e2.y);
        o1.z = fmaf(e3.z, n1.z, e3.x);
        o1.w = fmaf(e3.w, n1.w, e3.y);

        float4* op = (float4*)(out + (v0 << 1));
        op[0] = o0;
        op[1] = o1;
    }
}

extern "C" void kernel_launch(void* const* d_in, const int* in_sizes, int n_in,
                              void* d_out, int out_size, void* d_ws, size_t ws_size,
                              hipStream_t stream) {
    const int*   labels = (const int*)  d_in[0];  // [2,160,160,160,1] int32
    const float* means  = (const float*)d_in[1];  // [2,25,2] f32
    const float* stds   = (const float*)d_in[2];  // [2,25,2] f32
    const float* noise  = (const float*)d_in[3];  // [2,160,160,160,2] f32
    float* out = (float*)d_out;                   // [2,160,160,160,2] f32

    const int threads = 256;
    const int blocks = NTHREADS_TOT / threads;    // 2000
    gmm_sample_kernel<<<blocks, threads, 0, stream>>>(labels, means, stds, noise, out);
}

// Round 9
// 140.599 us; speedup vs baseline: 1.0278x; 1.0242x over previous
//
#include <hip/hip_runtime.h>

// Problem constants (compile-time, from reference):
//   B=2, D=H=W=160, C=2, N_LABELS=25, MAX_LABEL=48
//   voxels/batch V = 160^3 = 4,096,000 ; total voxels = 8,192,000
#define VPB   4096000
#define NLAB  25
#define MAXL  48
#define TOTAL_VOX 8192000

// Inverse LUT: FreeSurfer label value -> row index in means/stds.
// GEN_LABELS = {0,2,3,4,5,7,8,10,11,12,13,14,15,16,17,18,24,26,28,41,42,43,44,46,47}
__device__ __constant__ int c_lut[MAXL] = {
    /* 0*/ 0, /* 1*/ 0, /* 2*/ 1, /* 3*/ 2, /* 4*/ 3, /* 5*/ 4, /* 6*/ 0, /* 7*/ 5,
    /* 8*/ 6, /* 9*/ 0, /*10*/ 7, /*11*/ 8, /*12*/ 9, /*13*/10, /*14*/11, /*15*/12,
    /*16*/13, /*17*/14, /*18*/15, /*19*/ 0, /*20*/ 0, /*21*/ 0, /*22*/ 0, /*23*/ 0,
    /*24*/16, /*25*/ 0, /*26*/17, /*27*/ 0, /*28*/18, /*29*/ 0, /*30*/ 0, /*31*/ 0,
    /*32*/ 0, /*33*/ 0, /*34*/ 0, /*35*/ 0, /*36*/ 0, /*37*/ 0, /*38*/ 0, /*39*/ 0,
    /*40*/ 0, /*41*/19, /*42*/20, /*43*/21, /*44*/22, /*45*/ 0, /*46*/23, /*47*/24
};

// Round-9: 2 voxels/thread, 16000 blocks x 256. The measured trend across
// r1/r4/r5 is monotone (4vox 43.5 < 8vox 46.6 < 16vox 47.7 us): throughput
// is wave-completion-rate bound (serial label->gather->store chain/wave),
// so SHORTER wave lifetimes + more blocks win. This is the minimal chunk
// that keeps vectorized (8 B) label loads.
// Round-3 lesson: NO nontemporal stores (1.74x WRITE_SIZE amplification).
__global__ __launch_bounds__(256) void gmm_sample_kernel(
    const int*   __restrict__ labels,   // [B*V] (trailing dim 1 squeezed)
    const float* __restrict__ means,    // [B, 25, 2]
    const float* __restrict__ stds,     // [B, 25, 2]
    const float* __restrict__ noise,    // [B*V, 2]
    float*       __restrict__ out)      // [B*V, 2]
{
    __shared__ float4 table[2 * MAXL];

    const int tid = threadIdx.x;
    const int g   = blockIdx.x * 256 + tid;     // thread id, < 4,096,000
    const int v0  = g << 1;                     // first voxel, < 8,192,000

    // ---- stream loads first: in flight during table build + barrier ----
    const int2   lab = *(const int2*)  (labels + v0);
    const float4 n0  = *(const float4*)(noise + ((size_t)v0 << 1));

    // ---- fused per-(batch,label-value) table: (mean0, mean1, std0, std1) ----
    if (tid < 2 * MAXL) {
        const int b = tid / MAXL;
        const int v = tid - b * MAXL;
        const int row = c_lut[v];
        const float* mp = means + ((b * NLAB + row) << 1);
        const float* sp = stds  + ((b * NLAB + row) << 1);
        table[tid] = make_float4(mp[0], mp[1], sp[0], sp[1]);
    }
    __syncthreads();

    // Batch boundary (4,096,000) is a multiple of 2 -> both voxels same batch.
    const int boff = (v0 >= VPB) ? MAXL : 0;

    const float4 e0 = table[boff + lab.x];
    const float4 e1 = table[boff + lab.y];

    float4 o0;
    o0.x = fmaf(e0.z, n0.x, e0.x);
    o0.y = fmaf(e0.w, n0.y, e0.y);
    o0.z = fmaf(e1.z, n0.z, e1.x);
    o0.w = fmaf(e1.w, n0.w, e1.y);

    *(float4*)(out + ((size_t)v0 << 1)) = o0;
}

extern "C" void kernel_launch(void* const* d_in, const int* in_sizes, int n_in,
                              void* d_out, int out_size, void* d_ws, size_t ws_size,
                              hipStream_t stream) {
    const int*   labels = (const int*)  d_in[0];  // [2,160,160,160,1] int32
    const float* means  = (const float*)d_in[1];  // [2,25,2] f32
    const float* stds   = (const float*)d_in[2];  // [2,25,2] f32
    const float* noise  = (const float*)d_in[3];  // [2,160,160,160,2] f32
    float* out = (float*)d_out;                   // [2,160,160,160,2] f32

    const int threads = 256;
    const int total_threads = TOTAL_VOX / 2;      // 4,096,000
    const int blocks = total_threads / threads;   // 16000
    gmm_sample_kernel<<<blocks, threads, 0, stream>>>(labels, means, stds, noise, out);
}